// Round 2
// baseline (183.523 us; speedup 1.0000x reference)
//
#include <hip/hip_runtime.h>
#include <hip/hip_bf16.h>

#define NN   50000
#define EE   1600000
#define FIN  128
#define FOUT 64
#define BETA  0.5f
#define ALPHA 0.2f
#define SBW    256          // src rows per super-bucket
#define NB2    196          // ceil(NN/SBW)
#define RCAP   9000         // fixed region capacity (mean 8163 + ~9 sigma)
#define PGRID  400          // partition blocks
#define PCHUNK 4000         // EE/PGRID exact; 4 edges/thread at 1024 threads
#define CAP3   9008         // LDS record cache (covers full RCAP)
#define XS     136          // gemm X LDS stride (bf16 elems, 16B-aligned rows)
#define WS     136          // gemm W LDS stride (2-way max bank aliasing = free)

typedef __attribute__((ext_vector_type(8))) short short8;
typedef __attribute__((ext_vector_type(8))) unsigned short ushort8v;
typedef __attribute__((ext_vector_type(4))) float float4v;

__device__ __forceinline__ float load_any(const void* p, long i, int isf32) {
    if (isf32) return ((const float*)p)[i];
    unsigned int b = ((unsigned int)(((const unsigned short*)p)[i])) << 16;
    return __uint_as_float(b);
}

__device__ __forceinline__ unsigned short f32_to_bf16_rne(float f) {
    unsigned int b = __float_as_uint(f);
    return (unsigned short)((b + 0x7FFF + ((b >> 16) & 1)) >> 16);
}

__device__ __forceinline__ float bf16_to_f32(unsigned short u) {
    return __uint_as_float(((unsigned int)u) << 16);
}

// ---------------------------------------------------------------------------
// Kernel 1: fused detect + W-transpose + MFMA gemm.
// Each block self-detects dtypes from its own samples (bf16-reinterpret
// heuristic; P(block-level wrong vote) ~ 0.55^64 ~ 3e-17). W is staged to
// LDS bf16 per block (32 KB L2-hot read; padded stride -> free 2-way bank
// aliasing). Block 0 additionally probes Mv, publishes flags, zeroes bcur.
// ---------------------------------------------------------------------------
__global__ __launch_bounds__(256) void mfma_gemm_kernel(
    const void* __restrict__ inp,
    const void* __restrict__ W,
    const void* __restrict__ a,
    const void* __restrict__ Mv,
    unsigned short* __restrict__ h,
    float* __restrict__ s1,
    float* __restrict__ s2,
    int* __restrict__ flags,
    int* __restrict__ bcur)
{
    __shared__ unsigned short Xs[16 * XS];   // 4.25 KB
    __shared__ unsigned short Wl[64 * WS];   // 17 KB
    __shared__ float part1[4][16];
    __shared__ float part2[4][16];
    __shared__ int vote;

    const int tid  = threadIdx.x;
    const int wave = tid >> 6;
    const int lane = tid & 63;
    const int quad = lane >> 4;
    const int col  = lane & 15;
    const int rb   = blockIdx.x * 16;

    if (tid == 0) vote = 0;
    __syncthreads();

    {   // dtype probes, combined into one bitmask atomic
        int m = 0;
        const unsigned short* ip = (const unsigned short*)inp;
        const float vi = bf16_to_f32(ip[(long)rb * FIN + tid * 8]);   // 256 samples in-block
        if (isnan(vi) || fabsf(vi) > 1e4f) m |= 1;                    // fI
        if (tid < 128) {                                              // a: 128 samples (256 B, valid min size)
            const float va = bf16_to_f32(((const unsigned short*)a)[tid]);
            if (isnan(va) || fabsf(va) > 1e4f) m |= 2;                // fA
        }
        const float vw = bf16_to_f32(((const unsigned short*)W)[tid * 16]);
        if (isnan(vw) || fabsf(vw) > 1e4f) m |= 4;                    // fW
        if (blockIdx.x == 0) {                                        // Mv: block 0 only
            const long half = (long)EE >> 1;
            const long pos = 2 * (((long)tid * (half / 256)) % half);
            const float vm = bf16_to_f32(((const unsigned short*)Mv)[pos]);
            if (isnan(vm) || fabsf(vm) > 1e4f) m |= 8;                // fM
        }
        if (m) atomicOr(&vote, m);
    }
    __syncthreads();
    const int vm = vote;
    const int fI = vm & 1, fA = (vm >> 1) & 1, fW = (vm >> 2) & 1;

    if (blockIdx.x == 0) {
        if (tid == 0) { flags[0] = fI; flags[1] = (vm >> 3) & 1; }
        if (tid < NB2) bcur[tid] = 0;
    }

    // --- stage W -> LDS bf16 [64][WS] (read coalesced, scatter-transpose) ---
    for (int i = tid; i < FIN * FOUT; i += 256) {
        const int k = i >> 6, n = i & 63;
        Wl[n * WS + k] = f32_to_bf16_rne(load_any(W, i, fW));
    }
    // --- stage X -> LDS bf16 ---
    {
        const int r = tid >> 4, k8 = (tid & 15) * 8;
        if (!fI) {
            const unsigned short* src = (const unsigned short*)inp + (long)(rb + r) * FIN + k8;
            *(ushort8v*)&Xs[r * XS + k8] = *(const ushort8v*)src;
        } else {
            const float* src = (const float*)inp + (long)(rb + r) * FIN + k8;
            ushort8v v;
            #pragma unroll
            for (int j = 0; j < 8; ++j) v[j] = f32_to_bf16_rne(src[j]);
            *(ushort8v*)&Xs[r * XS + k8] = v;
        }
    }
    __syncthreads();

    const int nb = wave * 16;
    float4v acc = { 0.f, 0.f, 0.f, 0.f };
    #pragma unroll
    for (int k0 = 0; k0 < FIN; k0 += 32) {
        const short8 af = *(const short8*)&Xs[col * XS + k0 + quad * 8];
        const short8 bf = *(const short8*)&Wl[(nb + col) * WS + k0 + quad * 8];
        acc = __builtin_amdgcn_mfma_f32_16x16x32_bf16(af, bf, acc, 0, 0, 0);
    }

    #pragma unroll
    for (int r = 0; r < 4; ++r)
        h[(long)(rb + quad * 4 + r) * FOUT + nb + col] = f32_to_bf16_rne(acc[r]);

    const float a1 = load_any(a, nb + col, fA);
    const float a2 = load_any(a, 64 + nb + col, fA);
    #pragma unroll
    for (int r = 0; r < 4; ++r) {
        float v1 = acc[r] * a1;
        float v2 = acc[r] * a2;
        #pragma unroll
        for (int o = 1; o < 16; o <<= 1) {
            v1 += __shfl_xor(v1, o, 64);
            v2 += __shfl_xor(v2, o, 64);
        }
        if (col == 0) {
            part1[wave][quad * 4 + r] = v1;
            part2[wave][quad * 4 + r] = v2;
        }
    }
    __syncthreads();
    if (tid < 16) {
        s1[rb + tid] = part1[0][tid] + part1[1][tid] + part1[2][tid] + part1[3][tid];
        s2[rb + tid] = part2[0][tid] + part2[1][tid] + part2[2][tid] + part2[3][tid];
    }
}

// ---------------------------------------------------------------------------
// Kernel 2: partition into 196 super-buckets with FIXED regions (b*RCAP).
// Record: src<<32 | dst<<16 | bf16(edge_e).
// ---------------------------------------------------------------------------
__global__ __launch_bounds__(1024) void partition_kernel(
    const int* __restrict__ edge,
    const void* __restrict__ Mv,
    const int* __restrict__ flags,
    const float* __restrict__ s1,
    const float* __restrict__ s2,
    int* __restrict__ bcur,              // [NB2], zeroed; per-bucket count
    unsigned long long* __restrict__ recs)
{
    __shared__ int lcnt[NB2];
    __shared__ int lbase[NB2];
    const int tid = threadIdx.x;
    const int fM = flags[1];
    const int e0 = blockIdx.x * PCHUNK;

    if (tid < NB2) lcnt[tid] = 0;
    __syncthreads();

    int srcs[4], dsts[4];
    float mvs[4];
    #pragma unroll
    for (int k = 0; k < 4; ++k) {
        const int e = e0 + tid + 1024 * k;
        const bool ok = (tid + 1024 * k) < PCHUNK;
        srcs[k] = ok ? edge[e] : -1;
        dsts[k] = ok ? edge[EE + e] : 0;
        mvs[k]  = ok ? load_any(Mv, e, fM) : 0.f;
    }
    #pragma unroll
    for (int k = 0; k < 4; ++k)
        if (srcs[k] >= 0) atomicAdd(&lcnt[srcs[k] >> 8], 1);
    __syncthreads();

    if (tid < NB2) {
        const int c = lcnt[tid];
        const int o = c ? atomicAdd(&bcur[tid], c) : 0;
        lbase[tid] = tid * RCAP + o;
        lcnt[tid] = 0;                 // reuse as rank counter
    }
    __syncthreads();

    float ss1[4], ss2[4];
    #pragma unroll
    for (int k = 0; k < 4; ++k) {
        ss1[k] = (srcs[k] >= 0) ? s1[srcs[k]] : 0.f;
        ss2[k] = (srcs[k] >= 0) ? s2[dsts[k]] : 0.f;
    }
    #pragma unroll
    for (int k = 0; k < 4; ++k) {
        if (srcs[k] < 0) continue;
        const float bias = mvs[k] * BETA + (1.f - BETA);
        const float x  = ss1[k] + bias * ss2[k];
        const float lr = x > 0.f ? x : ALPHA * x;
        const float ee = __expf(lr);
        const int b = srcs[k] >> 8;
        const int r = atomicAdd(&lcnt[b], 1);
        const int pos = lbase[b] + r;
        if (pos < (b + 1) * RCAP)      // graceful guard (P ~ 1e-17)
            recs[pos] = ((unsigned long long)(unsigned)srcs[k] << 32)
                      | ((unsigned long long)(unsigned)dsts[k] << 16)
                      | (unsigned long long)f32_to_bf16_rne(ee);
    }
}

// ---------------------------------------------------------------------------
// Kernel 3: fused CSR finalize + SpMM + finalize. The bucket's records are
// fully LDS-resident (lrec 72 KB), reordered into row-grouped LDS pairs
// (lpair 36 KB) — pairs/rowbeg/rowend never touch global. SpMM phase: 16
// waves x 16 rows each, 8 lanes/edge x 16 B h-gathers.
// ---------------------------------------------------------------------------
__global__ __launch_bounds__(1024) void csr_spmm_kernel(
    const int* __restrict__ bcur,
    const unsigned long long* __restrict__ recs,
    const unsigned short* __restrict__ h,   // bf16 [NN, FOUT]
    const int* __restrict__ flags,
    void* __restrict__ out)
{
    __shared__ unsigned long long lrec[CAP3];   // 72 KB
    __shared__ unsigned int lpair[CAP3];        // 36 KB
    __shared__ int cnt[SBW];
    __shared__ int off[SBW];
    __shared__ int wsum[4];
    const int b    = blockIdx.x;
    const int tid  = threadIdx.x;
    const int rb   = b * SBW;
    const int beg  = b * RCAP;

    int n = bcur[b]; if (n > RCAP) n = RCAP;

    if (tid < SBW) cnt[tid] = 0;
    __syncthreads();

    for (int j = tid; j < n; j += 1024) {
        const unsigned long long rec = recs[beg + j];
        lrec[j] = rec;
        atomicAdd(&cnt[(int)(rec >> 32) - rb], 1);
    }
    __syncthreads();

    int c = 0, x = 0;
    if (tid < SBW) {
        const int lane = tid & 63;
        c = cnt[tid];
        x = c;
        #pragma unroll
        for (int o = 1; o < 64; o <<= 1) {
            int y = __shfl_up(x, o, 64);
            if (lane >= o) x += y;
        }
        if (lane == 63) wsum[tid >> 6] = x;
    }
    __syncthreads();
    if (tid < SBW) {
        const int wv = tid >> 6;
        int wb = 0;
        for (int w = 0; w < wv; ++w) wb += wsum[w];
        off[tid] = wb + x - c;
        cnt[tid] = 0;                  // reuse as rank counter (restored to c by scatter)
    }
    __syncthreads();

    for (int j = tid; j < n; j += 1024) {
        const unsigned long long rec = lrec[j];
        const int r = (int)(rec >> 32) - rb;
        const int rank = atomicAdd(&cnt[r], 1);
        lpair[off[r] + rank] = (unsigned int)(rec & 0xFFFFFFFFu);
    }
    __syncthreads();

    // ---- SpMM phase: wave wv handles rows {wv, wv+16, ...} of this bucket ----
    const int wv   = tid >> 6;
    const int lane = tid & 63;
    const int g    = lane >> 3;          // which of 8 in-flight edges
    const int sl   = lane & 7;           // features 8*sl .. 8*sl+7
    const int fOut = flags[0];

    for (int rr = wv; rr < SBW; rr += 16) {
        const int row = rb + rr;
        if (row >= NN) break;
        const int jb = off[rr];
        const int je = jb + cnt[rr];

        float acc0 = 0.f, acc1 = 0.f, acc2 = 0.f, acc3 = 0.f;
        float acc4 = 0.f, acc5 = 0.f, acc6 = 0.f, acc7 = 0.f;
        float rsum = 0.f;
        int j = jb;
        for (; j + 15 < je; j += 16) {
            const unsigned int u0 = lpair[j + g];
            const unsigned int u1 = lpair[j + 8 + g];
            const ushort8v h0 = *(const ushort8v*)&h[(long)(u0 >> 16) * FOUT + 8 * sl];
            const ushort8v h1 = *(const ushort8v*)&h[(long)(u1 >> 16) * FOUT + 8 * sl];
            const float v0 = bf16_to_f32((unsigned short)(u0 & 0xFFFFu));
            const float v1 = bf16_to_f32((unsigned short)(u1 & 0xFFFFu));
            rsum += v0 + v1;
            acc0 = fmaf(v0, bf16_to_f32(h0[0]), acc0); acc0 = fmaf(v1, bf16_to_f32(h1[0]), acc0);
            acc1 = fmaf(v0, bf16_to_f32(h0[1]), acc1); acc1 = fmaf(v1, bf16_to_f32(h1[1]), acc1);
            acc2 = fmaf(v0, bf16_to_f32(h0[2]), acc2); acc2 = fmaf(v1, bf16_to_f32(h1[2]), acc2);
            acc3 = fmaf(v0, bf16_to_f32(h0[3]), acc3); acc3 = fmaf(v1, bf16_to_f32(h1[3]), acc3);
            acc4 = fmaf(v0, bf16_to_f32(h0[4]), acc4); acc4 = fmaf(v1, bf16_to_f32(h1[4]), acc4);
            acc5 = fmaf(v0, bf16_to_f32(h0[5]), acc5); acc5 = fmaf(v1, bf16_to_f32(h1[5]), acc5);
            acc6 = fmaf(v0, bf16_to_f32(h0[6]), acc6); acc6 = fmaf(v1, bf16_to_f32(h1[6]), acc6);
            acc7 = fmaf(v0, bf16_to_f32(h0[7]), acc7); acc7 = fmaf(v1, bf16_to_f32(h1[7]), acc7);
        }
        for (; j < je; j += 8) {
            if (j + g < je) {
                const unsigned int u = lpair[j + g];
                const ushort8v hv = *(const ushort8v*)&h[(long)(u >> 16) * FOUT + 8 * sl];
                const float v = bf16_to_f32((unsigned short)(u & 0xFFFFu));
                rsum += v;
                acc0 = fmaf(v, bf16_to_f32(hv[0]), acc0);
                acc1 = fmaf(v, bf16_to_f32(hv[1]), acc1);
                acc2 = fmaf(v, bf16_to_f32(hv[2]), acc2);
                acc3 = fmaf(v, bf16_to_f32(hv[3]), acc3);
                acc4 = fmaf(v, bf16_to_f32(hv[4]), acc4);
                acc5 = fmaf(v, bf16_to_f32(hv[5]), acc5);
                acc6 = fmaf(v, bf16_to_f32(hv[6]), acc6);
                acc7 = fmaf(v, bf16_to_f32(hv[7]), acc7);
            }
        }

        #pragma unroll
        for (int o = 8; o < 64; o <<= 1) {
            rsum += __shfl_xor(rsum, o, 64);
            acc0 += __shfl_xor(acc0, o, 64);
            acc1 += __shfl_xor(acc1, o, 64);
            acc2 += __shfl_xor(acc2, o, 64);
            acc3 += __shfl_xor(acc3, o, 64);
            acc4 += __shfl_xor(acc4, o, 64);
            acc5 += __shfl_xor(acc5, o, 64);
            acc6 += __shfl_xor(acc6, o, 64);
            acc7 += __shfl_xor(acc7, o, 64);
        }

        if (g == 0) {
            const float inv = 1.f / rsum;
            float q0 = acc0 * inv, q1 = acc1 * inv, q2 = acc2 * inv, q3 = acc3 * inv;
            float q4 = acc4 * inv, q5 = acc5 * inv, q6 = acc6 * inv, q7 = acc7 * inv;
            q0 = q0 > 0.f ? q0 : (__expf(q0) - 1.f);
            q1 = q1 > 0.f ? q1 : (__expf(q1) - 1.f);
            q2 = q2 > 0.f ? q2 : (__expf(q2) - 1.f);
            q3 = q3 > 0.f ? q3 : (__expf(q3) - 1.f);
            q4 = q4 > 0.f ? q4 : (__expf(q4) - 1.f);
            q5 = q5 > 0.f ? q5 : (__expf(q5) - 1.f);
            q6 = q6 > 0.f ? q6 : (__expf(q6) - 1.f);
            q7 = q7 > 0.f ? q7 : (__expf(q7) - 1.f);
            if (fOut) {
                float4* o = (float4*)((float*)out + (long)row * FOUT + 8 * sl);
                o[0] = make_float4(q0, q1, q2, q3);
                o[1] = make_float4(q4, q5, q6, q7);
            } else {
                ushort8v ov;
                ov[0] = f32_to_bf16_rne(q0); ov[1] = f32_to_bf16_rne(q1);
                ov[2] = f32_to_bf16_rne(q2); ov[3] = f32_to_bf16_rne(q3);
                ov[4] = f32_to_bf16_rne(q4); ov[5] = f32_to_bf16_rne(q5);
                ov[6] = f32_to_bf16_rne(q6); ov[7] = f32_to_bf16_rne(q7);
                *(ushort8v*)((unsigned short*)out + (long)row * FOUT + 8 * sl) = ov;
            }
        }
    }
}

extern "C" void kernel_launch(void* const* d_in, const int* in_sizes, int n_in,
                              void* d_out, int out_size, void* d_ws, size_t ws_size,
                              hipStream_t stream) {
    const void* inp  = d_in[0];
    const void* Mv   = d_in[1];
    const void* W    = d_in[2];
    const void* a    = d_in[3];
    const int*  edge = (const int*)d_in[4];

    // ws: flags | h bf16[NN*64] | s1[NN] | s2[NN] | bcur[NB2] | recs u64[NB2*RCAP]
    char* p = (char*)d_ws;
    int*                flags  = (int*)p;            p += 256;
    unsigned short*     h      = (unsigned short*)p; p += ((size_t)NN * FOUT * 2 + 255) / 256 * 256;
    float*              s1     = (float*)p;          p += ((size_t)NN * 4 + 255) / 256 * 256;
    float*              s2     = (float*)p;          p += ((size_t)NN * 4 + 255) / 256 * 256;
    int*                bcur   = (int*)p;            p += ((size_t)NB2 * 4 + 255) / 256 * 256;
    unsigned long long* recs   = (unsigned long long*)p;

    mfma_gemm_kernel<<<NN / 16, 256, 0, stream>>>(inp, W, a, Mv, h, s1, s2, flags, bcur);
    partition_kernel<<<PGRID, 1024, 0, stream>>>(edge, Mv, flags, s1, s2, bcur, recs);
    csr_spmm_kernel<<<NB2, 1024, 0, stream>>>(bcur, recs, h, flags, d_out);
}

// Round 3
// 174.465 us; speedup vs baseline: 1.0519x; 1.0519x over previous
//
#include <hip/hip_runtime.h>
#include <hip/hip_bf16.h>

#define NN   50000
#define EE   1600000
#define FIN  128
#define FOUT 64
#define BETA  0.5f
#define ALPHA 0.2f
#define SBW    256          // src rows per super-bucket
#define NB2    196          // ceil(NN/SBW)
#define RCAP   9000         // fixed region capacity (mean 8163 + ~9 sigma)
#define PGRID  400          // partition blocks
#define PCHUNK 4000         // EE/PGRID exact; 4 edges/thread at 1024 threads
#define CAP3   9008         // LDS record cache (covers full RCAP)
#define XS     136          // gemm X LDS stride (bf16 elems, 16B-aligned rows)

typedef __attribute__((ext_vector_type(8))) short short8;
typedef __attribute__((ext_vector_type(8))) unsigned short ushort8v;
typedef __attribute__((ext_vector_type(4))) float float4v;

__device__ __forceinline__ float load_any(const void* p, long i, int isf32) {
    if (isf32) return ((const float*)p)[i];
    unsigned int b = ((unsigned int)(((const unsigned short*)p)[i])) << 16;
    return __uint_as_float(b);
}

__device__ __forceinline__ unsigned short f32_to_bf16_rne(float f) {
    unsigned int b = __float_as_uint(f);
    return (unsigned short)((b + 0x7FFF + ((b >> 16) & 1)) >> 16);
}

__device__ __forceinline__ float bf16_to_f32(unsigned short u) {
    return __uint_as_float(((unsigned int)u) << 16);
}

// ---------------------------------------------------------------------------
// Kernel 0: fused detect(W,Mv) + W transpose -> Wt bf16 [64][128] + bcur zero.
// Per-block self-vote on fW (256 even-index u16 samples; fp32 low-halves are
// random bits -> P(miss) ~ 0.55^256). Block 0 also votes fM -> flags[1].
// ---------------------------------------------------------------------------
__global__ __launch_bounds__(256) void detwt_kernel(
    const void* __restrict__ W, const void* __restrict__ Mv,
    unsigned short* __restrict__ Wt, int* __restrict__ flags,
    int* __restrict__ bcur)
{
    __shared__ int vote;
    const int tid = threadIdx.x;
    if (tid == 0) vote = 0;
    __syncthreads();

    int m = 0;
    const float vw = bf16_to_f32(((const unsigned short*)W)[tid * 16]);
    if (isnan(vw) || fabsf(vw) > 1e4f) m |= 1;
    if (blockIdx.x == 0) {
        const long half = (long)EE >> 1;
        const long pos = 2 * (((long)tid * (half / 256)) % half);
        const float vm = bf16_to_f32(((const unsigned short*)Mv)[pos]);
        if (isnan(vm) || fabsf(vm) > 1e4f) m |= 2;
    }
    if (m) atomicOr(&vote, m);
    __syncthreads();

    const int fW = vote & 1;
    if (blockIdx.x == 0) {
        if (tid == 0) flags[1] = (vote >> 1) & 1;
        if (tid < NB2) bcur[tid] = 0;
    }
    const int i = blockIdx.x * 256 + tid;          // grid = 32 blocks, i < 8192
    const int k = i >> 6, n = i & 63;              // read W coalesced
    Wt[n * FIN + k] = f32_to_bf16_rne(load_any(W, i, fW));
}

// ---------------------------------------------------------------------------
// Kernel 1: MFMA gemm (R1-validated form). 16 rows/block; X staged via one
// 16 B vector load/thread; B-fragments direct from global Wt (L1-hot 16 KB).
// Self-detects fI/fA; block 0 publishes flags[0]=fI for the spmm epilogue.
// ---------------------------------------------------------------------------
__global__ __launch_bounds__(256) void mfma_gemm_kernel(
    const void* __restrict__ inp,
    const unsigned short* __restrict__ Wt,   // bf16 [64][128]
    const void* __restrict__ a,
    unsigned short* __restrict__ h,
    float* __restrict__ s1,
    float* __restrict__ s2,
    int* __restrict__ flags)
{
    __shared__ unsigned short Xs[16 * XS];   // 4.25 KB
    __shared__ float part1[4][16];
    __shared__ float part2[4][16];
    __shared__ int vote;

    const int tid  = threadIdx.x;
    const int wave = tid >> 6;
    const int lane = tid & 63;
    const int quad = lane >> 4;
    const int col  = lane & 15;
    const int rb   = blockIdx.x * 16;

    if (tid == 0) vote = 0;
    __syncthreads();

    {   // dtype probes over this block's own rows (in-bounds for bf16 size)
        int m = 0;
        const float vi = bf16_to_f32(((const unsigned short*)inp)[(long)rb * FIN + tid * 8]);
        if (isnan(vi) || fabsf(vi) > 1e4f) m |= 1;                    // fI
        if (tid < 128) {
            const float va = bf16_to_f32(((const unsigned short*)a)[tid]);
            if (isnan(va) || fabsf(va) > 1e4f) m |= 2;                // fA
        }
        if (m) atomicOr(&vote, m);
    }
    __syncthreads();
    const int fI = vote & 1, fA = (vote >> 1) & 1;
    if (blockIdx.x == 0 && tid == 0) flags[0] = fI;

    {   // stage X -> LDS bf16
        const int r = tid >> 4, k8 = (tid & 15) * 8;
        if (!fI) {
            const unsigned short* src = (const unsigned short*)inp + (long)(rb + r) * FIN + k8;
            *(ushort8v*)&Xs[r * XS + k8] = *(const ushort8v*)src;
        } else {
            const float* src = (const float*)inp + (long)(rb + r) * FIN + k8;
            ushort8v v;
            #pragma unroll
            for (int j = 0; j < 8; ++j) v[j] = f32_to_bf16_rne(src[j]);
            *(ushort8v*)&Xs[r * XS + k8] = v;
        }
    }
    __syncthreads();

    const int nb = wave * 16;
    float4v acc = { 0.f, 0.f, 0.f, 0.f };
    #pragma unroll
    for (int k0 = 0; k0 < FIN; k0 += 32) {
        const short8 af = *(const short8*)&Xs[col * XS + k0 + quad * 8];
        const short8 bf = *(const short8*)&Wt[(long)(nb + col) * FIN + k0 + quad * 8];
        acc = __builtin_amdgcn_mfma_f32_16x16x32_bf16(af, bf, acc, 0, 0, 0);
    }

    #pragma unroll
    for (int r = 0; r < 4; ++r)
        h[(long)(rb + quad * 4 + r) * FOUT + nb + col] = f32_to_bf16_rne(acc[r]);

    const float a1 = load_any(a, nb + col, fA);
    const float a2 = load_any(a, 64 + nb + col, fA);
    #pragma unroll
    for (int r = 0; r < 4; ++r) {
        float v1 = acc[r] * a1;
        float v2 = acc[r] * a2;
        #pragma unroll
        for (int o = 1; o < 16; o <<= 1) {
            v1 += __shfl_xor(v1, o, 64);
            v2 += __shfl_xor(v2, o, 64);
        }
        if (col == 0) {
            part1[wave][quad * 4 + r] = v1;
            part2[wave][quad * 4 + r] = v2;
        }
    }
    __syncthreads();
    if (tid < 16) {
        s1[rb + tid] = part1[0][tid] + part1[1][tid] + part1[2][tid] + part1[3][tid];
        s2[rb + tid] = part2[0][tid] + part2[1][tid] + part2[2][tid] + part2[3][tid];
    }
}

// ---------------------------------------------------------------------------
// Kernel 2: partition into 196 super-buckets with FIXED regions (b*RCAP).
// Record: src<<32 | dst<<16 | bf16(edge_e).
// ---------------------------------------------------------------------------
__global__ __launch_bounds__(1024) void partition_kernel(
    const int* __restrict__ edge,
    const void* __restrict__ Mv,
    const int* __restrict__ flags,
    const float* __restrict__ s1,
    const float* __restrict__ s2,
    int* __restrict__ bcur,              // [NB2], zeroed; per-bucket count
    unsigned long long* __restrict__ recs)
{
    __shared__ int lcnt[NB2];
    __shared__ int lbase[NB2];
    const int tid = threadIdx.x;
    const int fM = flags[1];
    const int e0 = blockIdx.x * PCHUNK;

    if (tid < NB2) lcnt[tid] = 0;
    __syncthreads();

    int srcs[4], dsts[4];
    float mvs[4];
    #pragma unroll
    for (int k = 0; k < 4; ++k) {
        const int e = e0 + tid + 1024 * k;
        const bool ok = (tid + 1024 * k) < PCHUNK;
        srcs[k] = ok ? edge[e] : -1;
        dsts[k] = ok ? edge[EE + e] : 0;
        mvs[k]  = ok ? load_any(Mv, e, fM) : 0.f;
    }
    #pragma unroll
    for (int k = 0; k < 4; ++k)
        if (srcs[k] >= 0) atomicAdd(&lcnt[srcs[k] >> 8], 1);
    __syncthreads();

    if (tid < NB2) {
        const int c = lcnt[tid];
        const int o = c ? atomicAdd(&bcur[tid], c) : 0;
        lbase[tid] = tid * RCAP + o;
        lcnt[tid] = 0;                 // reuse as rank counter
    }
    __syncthreads();

    float ss1[4], ss2[4];
    #pragma unroll
    for (int k = 0; k < 4; ++k) {
        ss1[k] = (srcs[k] >= 0) ? s1[srcs[k]] : 0.f;
        ss2[k] = (srcs[k] >= 0) ? s2[dsts[k]] : 0.f;
    }
    #pragma unroll
    for (int k = 0; k < 4; ++k) {
        if (srcs[k] < 0) continue;
        const float bias = mvs[k] * BETA + (1.f - BETA);
        const float x  = ss1[k] + bias * ss2[k];
        const float lr = x > 0.f ? x : ALPHA * x;
        const float ee = __expf(lr);
        const int b = srcs[k] >> 8;
        const int r = atomicAdd(&lcnt[b], 1);
        const int pos = lbase[b] + r;
        if (pos < (b + 1) * RCAP)      // graceful guard (P ~ 1e-17)
            recs[pos] = ((unsigned long long)(unsigned)srcs[k] << 32)
                      | ((unsigned long long)(unsigned)dsts[k] << 16)
                      | (unsigned long long)f32_to_bf16_rne(ee);
    }
}

// ---------------------------------------------------------------------------
// Kernel 3: fused CSR finalize + SpMM + finalize.
// R3: ranks computed in pass 1 (stashed in record high bits) -> scatter pass
// has zero atomics; SpMM unrolled to 32 edges/iter = 4 gathers in flight
// per lane (was 2) to attack the measured latency bound (VALUBusy 33%).
// ---------------------------------------------------------------------------
__global__ __launch_bounds__(1024) void csr_spmm_kernel(
    const int* __restrict__ bcur,
    const unsigned long long* __restrict__ recs,
    const unsigned short* __restrict__ h,   // bf16 [NN, FOUT]
    const int* __restrict__ flags,
    void* __restrict__ out)
{
    __shared__ unsigned long long lrec[CAP3];   // 72 KB
    __shared__ unsigned int lpair[CAP3];        // 36 KB
    __shared__ int cnt[SBW];
    __shared__ int off[SBW];
    __shared__ int wsum[4];
    const int b    = blockIdx.x;
    const int tid  = threadIdx.x;
    const int rb   = b * SBW;
    const int beg  = b * RCAP;

    int n = bcur[b]; if (n > RCAP) n = RCAP;

    if (tid < SBW) cnt[tid] = 0;
    __syncthreads();

    // pass 1: load + count + rank; repack hi32 = r | rank<<8 (r<256, rank<2^14)
    for (int j = tid; j < n; j += 1024) {
        const unsigned long long rec = recs[beg + j];
        const int r = (int)(rec >> 32) - rb;
        const int rank = atomicAdd(&cnt[r], 1);
        lrec[j] = ((unsigned long long)(unsigned)(r | (rank << 8)) << 32)
                | (unsigned long long)(unsigned)(rec & 0xFFFFFFFFu);
    }
    __syncthreads();

    // exclusive scan of cnt -> off (cnt preserved: it is the row length)
    int c = 0, x = 0;
    if (tid < SBW) {
        const int lane = tid & 63;
        c = cnt[tid];
        x = c;
        #pragma unroll
        for (int o = 1; o < 64; o <<= 1) {
            int y = __shfl_up(x, o, 64);
            if (lane >= o) x += y;
        }
        if (lane == 63) wsum[tid >> 6] = x;
    }
    __syncthreads();
    if (tid < SBW) {
        const int wv = tid >> 6;
        int wb = 0;
        for (int w = 0; w < wv; ++w) wb += wsum[w];
        off[tid] = wb + x - c;
    }
    __syncthreads();

    // pass 2: atomic-free scatter into row-grouped lpair
    for (int j = tid; j < n; j += 1024) {
        const unsigned long long rec = lrec[j];
        const unsigned int hi = (unsigned int)(rec >> 32);
        lpair[off[hi & 255u] + (hi >> 8)] = (unsigned int)(rec & 0xFFFFFFFFu);
    }
    __syncthreads();

    // ---- SpMM phase: wave wv handles rows {wv, wv+16, ...} of this bucket ----
    const int wv   = tid >> 6;
    const int lane = tid & 63;
    const int g    = lane >> 3;          // which of 8 edge slots
    const int sl   = lane & 7;           // features 8*sl .. 8*sl+7
    const int fOut = flags[0];

    for (int rr = wv; rr < SBW; rr += 16) {
        const int row = rb + rr;
        if (row >= NN) break;
        const int jb = off[rr];
        const int je = jb + cnt[rr];

        float acc0 = 0.f, acc1 = 0.f, acc2 = 0.f, acc3 = 0.f;
        float acc4 = 0.f, acc5 = 0.f, acc6 = 0.f, acc7 = 0.f;
        float rsum = 0.f;
        int j = jb;
        for (; j + 31 < je; j += 32) {   // 32 edges, 4 gathers in flight/lane
            unsigned int u[4];
            #pragma unroll
            for (int kk = 0; kk < 4; ++kk) u[kk] = lpair[j + 8 * kk + g];
            ushort8v hv[4];
            #pragma unroll
            for (int kk = 0; kk < 4; ++kk)
                hv[kk] = *(const ushort8v*)&h[(long)(u[kk] >> 16) * FOUT + 8 * sl];
            #pragma unroll
            for (int kk = 0; kk < 4; ++kk) {
                const float v = bf16_to_f32((unsigned short)(u[kk] & 0xFFFFu));
                rsum += v;
                acc0 = fmaf(v, bf16_to_f32(hv[kk][0]), acc0);
                acc1 = fmaf(v, bf16_to_f32(hv[kk][1]), acc1);
                acc2 = fmaf(v, bf16_to_f32(hv[kk][2]), acc2);
                acc3 = fmaf(v, bf16_to_f32(hv[kk][3]), acc3);
                acc4 = fmaf(v, bf16_to_f32(hv[kk][4]), acc4);
                acc5 = fmaf(v, bf16_to_f32(hv[kk][5]), acc5);
                acc6 = fmaf(v, bf16_to_f32(hv[kk][6]), acc6);
                acc7 = fmaf(v, bf16_to_f32(hv[kk][7]), acc7);
            }
        }
        for (; j + 7 < je; j += 8) {     // full single-group steps
            const unsigned int u = lpair[j + g];
            const ushort8v hv = *(const ushort8v*)&h[(long)(u >> 16) * FOUT + 8 * sl];
            const float v = bf16_to_f32((unsigned short)(u & 0xFFFFu));
            rsum += v;
            acc0 = fmaf(v, bf16_to_f32(hv[0]), acc0);
            acc1 = fmaf(v, bf16_to_f32(hv[1]), acc1);
            acc2 = fmaf(v, bf16_to_f32(hv[2]), acc2);
            acc3 = fmaf(v, bf16_to_f32(hv[3]), acc3);
            acc4 = fmaf(v, bf16_to_f32(hv[4]), acc4);
            acc5 = fmaf(v, bf16_to_f32(hv[5]), acc5);
            acc6 = fmaf(v, bf16_to_f32(hv[6]), acc6);
            acc7 = fmaf(v, bf16_to_f32(hv[7]), acc7);
        }
        if (j < je && j + g < je) {      // tail
            const unsigned int u = lpair[j + g];
            const ushort8v hv = *(const ushort8v*)&h[(long)(u >> 16) * FOUT + 8 * sl];
            const float v = bf16_to_f32((unsigned short)(u & 0xFFFFu));
            rsum += v;
            acc0 = fmaf(v, bf16_to_f32(hv[0]), acc0);
            acc1 = fmaf(v, bf16_to_f32(hv[1]), acc1);
            acc2 = fmaf(v, bf16_to_f32(hv[2]), acc2);
            acc3 = fmaf(v, bf16_to_f32(hv[3]), acc3);
            acc4 = fmaf(v, bf16_to_f32(hv[4]), acc4);
            acc5 = fmaf(v, bf16_to_f32(hv[5]), acc5);
            acc6 = fmaf(v, bf16_to_f32(hv[6]), acc6);
            acc7 = fmaf(v, bf16_to_f32(hv[7]), acc7);
        }

        #pragma unroll
        for (int o = 8; o < 64; o <<= 1) {
            rsum += __shfl_xor(rsum, o, 64);
            acc0 += __shfl_xor(acc0, o, 64);
            acc1 += __shfl_xor(acc1, o, 64);
            acc2 += __shfl_xor(acc2, o, 64);
            acc3 += __shfl_xor(acc3, o, 64);
            acc4 += __shfl_xor(acc4, o, 64);
            acc5 += __shfl_xor(acc5, o, 64);
            acc6 += __shfl_xor(acc6, o, 64);
            acc7 += __shfl_xor(acc7, o, 64);
        }

        if (g == 0) {
            const float inv = 1.f / rsum;
            float q0 = acc0 * inv, q1 = acc1 * inv, q2 = acc2 * inv, q3 = acc3 * inv;
            float q4 = acc4 * inv, q5 = acc5 * inv, q6 = acc6 * inv, q7 = acc7 * inv;
            q0 = q0 > 0.f ? q0 : (__expf(q0) - 1.f);
            q1 = q1 > 0.f ? q1 : (__expf(q1) - 1.f);
            q2 = q2 > 0.f ? q2 : (__expf(q2) - 1.f);
            q3 = q3 > 0.f ? q3 : (__expf(q3) - 1.f);
            q4 = q4 > 0.f ? q4 : (__expf(q4) - 1.f);
            q5 = q5 > 0.f ? q5 : (__expf(q5) - 1.f);
            q6 = q6 > 0.f ? q6 : (__expf(q6) - 1.f);
            q7 = q7 > 0.f ? q7 : (__expf(q7) - 1.f);
            if (fOut) {
                float4* o = (float4*)((float*)out + (long)row * FOUT + 8 * sl);
                o[0] = make_float4(q0, q1, q2, q3);
                o[1] = make_float4(q4, q5, q6, q7);
            } else {
                ushort8v ov;
                ov[0] = f32_to_bf16_rne(q0); ov[1] = f32_to_bf16_rne(q1);
                ov[2] = f32_to_bf16_rne(q2); ov[3] = f32_to_bf16_rne(q3);
                ov[4] = f32_to_bf16_rne(q4); ov[5] = f32_to_bf16_rne(q5);
                ov[6] = f32_to_bf16_rne(q6); ov[7] = f32_to_bf16_rne(q7);
                *(ushort8v*)((unsigned short*)out + (long)row * FOUT + 8 * sl) = ov;
            }
        }
    }
}

extern "C" void kernel_launch(void* const* d_in, const int* in_sizes, int n_in,
                              void* d_out, int out_size, void* d_ws, size_t ws_size,
                              hipStream_t stream) {
    const void* inp  = d_in[0];
    const void* Mv   = d_in[1];
    const void* W    = d_in[2];
    const void* a    = d_in[3];
    const int*  edge = (const int*)d_in[4];

    // ws: flags | Wt bf16[64*128] | h bf16[NN*64] | s1[NN] | s2[NN] | bcur[NB2] | recs u64[NB2*RCAP]
    char* p = (char*)d_ws;
    int*                flags  = (int*)p;            p += 256;
    unsigned short*     Wt     = (unsigned short*)p; p += ((size_t)FOUT * FIN * 2 + 255) / 256 * 256;
    unsigned short*     h      = (unsigned short*)p; p += ((size_t)NN * FOUT * 2 + 255) / 256 * 256;
    float*              s1     = (float*)p;          p += ((size_t)NN * 4 + 255) / 256 * 256;
    float*              s2     = (float*)p;          p += ((size_t)NN * 4 + 255) / 256 * 256;
    int*                bcur   = (int*)p;            p += ((size_t)NB2 * 4 + 255) / 256 * 256;
    unsigned long long* recs   = (unsigned long long*)p;

    detwt_kernel<<<32, 256, 0, stream>>>(W, Mv, Wt, flags, bcur);
    mfma_gemm_kernel<<<NN / 16, 256, 0, stream>>>(inp, Wt, a, h, s1, s2, flags);
    partition_kernel<<<PGRID, 1024, 0, stream>>>(edge, Mv, flags, s1, s2, bcur, recs);
    csr_spmm_kernel<<<NB2, 1024, 0, stream>>>(bcur, recs, h, flags, d_out);
}

// Round 4
// 155.271 us; speedup vs baseline: 1.1820x; 1.1236x over previous
//
#include <hip/hip_runtime.h>
#include <hip/hip_bf16.h>

#define NN   50000
#define EE   1600000
#define FIN  128
#define FOUT 64
#define BETA  0.5f
#define ALPHA 0.2f
#define SBW    64           // src rows per bucket (R4: was 256 -> 4 blocks/CU)
#define SBSH   6            // log2(SBW)
#define NB     782          // ceil(NN/SBW)
#define RCAP   2500         // region capacity (mean 2048 + 10 sigma)
#define PGRID  400          // partition blocks
#define PCHUNK 4000         // EE/PGRID exact; 4 edges/thread at 1024 threads
#define CAPB   2504         // LDS record cache (covers RCAP)
#define XS     136          // gemm X LDS stride (bf16 elems, 16B-aligned rows)

typedef __attribute__((ext_vector_type(8))) short short8;
typedef __attribute__((ext_vector_type(8))) unsigned short ushort8v;
typedef __attribute__((ext_vector_type(4))) float float4v;

__device__ __forceinline__ float load_any(const void* p, long i, int isf32) {
    if (isf32) return ((const float*)p)[i];
    unsigned int b = ((unsigned int)(((const unsigned short*)p)[i])) << 16;
    return __uint_as_float(b);
}

__device__ __forceinline__ unsigned short f32_to_bf16_rne(float f) {
    unsigned int b = __float_as_uint(f);
    return (unsigned short)((b + 0x7FFF + ((b >> 16) & 1)) >> 16);
}

__device__ __forceinline__ float bf16_to_f32(unsigned short u) {
    return __uint_as_float(((unsigned int)u) << 16);
}

// ---------------------------------------------------------------------------
// Kernel 0: fused detect(W,Mv) + W transpose -> Wt bf16 [64][128] + bcur zero.
// ---------------------------------------------------------------------------
__global__ __launch_bounds__(256) void detwt_kernel(
    const void* __restrict__ W, const void* __restrict__ Mv,
    unsigned short* __restrict__ Wt, int* __restrict__ flags,
    int* __restrict__ bcur)
{
    __shared__ int vote;
    const int tid = threadIdx.x;
    if (tid == 0) vote = 0;
    __syncthreads();

    int m = 0;
    const float vw = bf16_to_f32(((const unsigned short*)W)[tid * 16]);
    if (isnan(vw) || fabsf(vw) > 1e4f) m |= 1;
    if (blockIdx.x == 0) {
        const long half = (long)EE >> 1;
        const long pos = 2 * (((long)tid * (half / 256)) % half);
        const float vm = bf16_to_f32(((const unsigned short*)Mv)[pos]);
        if (isnan(vm) || fabsf(vm) > 1e4f) m |= 2;
    }
    if (m) atomicOr(&vote, m);
    __syncthreads();

    const int fW = vote & 1;
    if (blockIdx.x == 0) {
        if (tid == 0) flags[1] = (vote >> 1) & 1;
        for (int i = tid; i < NB; i += 256) bcur[i] = 0;
    }
    const int i = blockIdx.x * 256 + tid;          // grid = 32 blocks, i < 8192
    const int k = i >> 6, n = i & 63;              // read W coalesced
    Wt[n * FIN + k] = f32_to_bf16_rne(load_any(W, i, fW));
}

// ---------------------------------------------------------------------------
// Kernel 1: MFMA gemm (R1-validated form). 16 rows/block; X staged via one
// 16 B vector load/thread; B-fragments direct from global Wt (L1-hot 16 KB).
// Self-detects fI/fA; block 0 publishes flags[0]=fI for the spmm epilogue.
// ---------------------------------------------------------------------------
__global__ __launch_bounds__(256) void mfma_gemm_kernel(
    const void* __restrict__ inp,
    const unsigned short* __restrict__ Wt,   // bf16 [64][128]
    const void* __restrict__ a,
    unsigned short* __restrict__ h,
    float* __restrict__ s1,
    float* __restrict__ s2,
    int* __restrict__ flags)
{
    __shared__ unsigned short Xs[16 * XS];   // 4.25 KB
    __shared__ float part1[4][16];
    __shared__ float part2[4][16];
    __shared__ int vote;

    const int tid  = threadIdx.x;
    const int wave = tid >> 6;
    const int lane = tid & 63;
    const int quad = lane >> 4;
    const int col  = lane & 15;
    const int rb   = blockIdx.x * 16;

    if (tid == 0) vote = 0;
    __syncthreads();

    {   // dtype probes over this block's own rows (in-bounds for bf16 size)
        int m = 0;
        const float vi = bf16_to_f32(((const unsigned short*)inp)[(long)rb * FIN + tid * 8]);
        if (isnan(vi) || fabsf(vi) > 1e4f) m |= 1;                    // fI
        if (tid < 128) {
            const float va = bf16_to_f32(((const unsigned short*)a)[tid]);
            if (isnan(va) || fabsf(va) > 1e4f) m |= 2;                // fA
        }
        if (m) atomicOr(&vote, m);
    }
    __syncthreads();
    const int fI = vote & 1, fA = (vote >> 1) & 1;
    if (blockIdx.x == 0 && tid == 0) flags[0] = fI;

    {   // stage X -> LDS bf16
        const int r = tid >> 4, k8 = (tid & 15) * 8;
        if (!fI) {
            const unsigned short* src = (const unsigned short*)inp + (long)(rb + r) * FIN + k8;
            *(ushort8v*)&Xs[r * XS + k8] = *(const ushort8v*)src;
        } else {
            const float* src = (const float*)inp + (long)(rb + r) * FIN + k8;
            ushort8v v;
            #pragma unroll
            for (int j = 0; j < 8; ++j) v[j] = f32_to_bf16_rne(src[j]);
            *(ushort8v*)&Xs[r * XS + k8] = v;
        }
    }
    __syncthreads();

    const int nb = wave * 16;
    float4v acc = { 0.f, 0.f, 0.f, 0.f };
    #pragma unroll
    for (int k0 = 0; k0 < FIN; k0 += 32) {
        const short8 af = *(const short8*)&Xs[col * XS + k0 + quad * 8];
        const short8 bf = *(const short8*)&Wt[(long)(nb + col) * FIN + k0 + quad * 8];
        acc = __builtin_amdgcn_mfma_f32_16x16x32_bf16(af, bf, acc, 0, 0, 0);
    }

    #pragma unroll
    for (int r = 0; r < 4; ++r)
        h[(long)(rb + quad * 4 + r) * FOUT + nb + col] = f32_to_bf16_rne(acc[r]);

    const float a1 = load_any(a, nb + col, fA);
    const float a2 = load_any(a, 64 + nb + col, fA);
    #pragma unroll
    for (int r = 0; r < 4; ++r) {
        float v1 = acc[r] * a1;
        float v2 = acc[r] * a2;
        #pragma unroll
        for (int o = 1; o < 16; o <<= 1) {
            v1 += __shfl_xor(v1, o, 64);
            v2 += __shfl_xor(v2, o, 64);
        }
        if (col == 0) {
            part1[wave][quad * 4 + r] = v1;
            part2[wave][quad * 4 + r] = v2;
        }
    }
    __syncthreads();
    if (tid < 16) {
        s1[rb + tid] = part1[0][tid] + part1[1][tid] + part1[2][tid] + part1[3][tid];
        s2[rb + tid] = part2[0][tid] + part2[1][tid] + part2[2][tid] + part2[3][tid];
    }
}

// ---------------------------------------------------------------------------
// Kernel 2: partition into 782 buckets with FIXED regions (b*RCAP).
// Record: src<<32 | dst<<16 | bf16(edge_e).
// ---------------------------------------------------------------------------
__global__ __launch_bounds__(1024) void partition_kernel(
    const int* __restrict__ edge,
    const void* __restrict__ Mv,
    const int* __restrict__ flags,
    const float* __restrict__ s1,
    const float* __restrict__ s2,
    int* __restrict__ bcur,              // [NB], zeroed; per-bucket count
    unsigned long long* __restrict__ recs)
{
    __shared__ int lcnt[NB];
    __shared__ int lbase[NB];
    const int tid = threadIdx.x;
    const int fM = flags[1];
    const int e0 = blockIdx.x * PCHUNK;

    if (tid < NB) lcnt[tid] = 0;
    __syncthreads();

    int srcs[4], dsts[4];
    float mvs[4];
    #pragma unroll
    for (int k = 0; k < 4; ++k) {
        const int e = e0 + tid + 1024 * k;
        const bool ok = (tid + 1024 * k) < PCHUNK;
        srcs[k] = ok ? edge[e] : -1;
        dsts[k] = ok ? edge[EE + e] : 0;
        mvs[k]  = ok ? load_any(Mv, e, fM) : 0.f;
    }
    #pragma unroll
    for (int k = 0; k < 4; ++k)
        if (srcs[k] >= 0) atomicAdd(&lcnt[srcs[k] >> SBSH], 1);
    __syncthreads();

    if (tid < NB) {
        const int c = lcnt[tid];
        const int o = c ? atomicAdd(&bcur[tid], c) : 0;
        lbase[tid] = tid * RCAP + o;
        lcnt[tid] = 0;                 // reuse as rank counter
    }
    __syncthreads();

    float ss1[4], ss2[4];
    #pragma unroll
    for (int k = 0; k < 4; ++k) {
        ss1[k] = (srcs[k] >= 0) ? s1[srcs[k]] : 0.f;
        ss2[k] = (srcs[k] >= 0) ? s2[dsts[k]] : 0.f;
    }
    #pragma unroll
    for (int k = 0; k < 4; ++k) {
        if (srcs[k] < 0) continue;
        const float bias = mvs[k] * BETA + (1.f - BETA);
        const float x  = ss1[k] + bias * ss2[k];
        const float lr = x > 0.f ? x : ALPHA * x;
        const float ee = __expf(lr);
        const int b = srcs[k] >> SBSH;
        const int r = atomicAdd(&lcnt[b], 1);
        const int pos = lbase[b] + r;
        if (pos < (b + 1) * RCAP)      // graceful guard (P ~ 1e-22)
            recs[pos] = ((unsigned long long)(unsigned)srcs[k] << 32)
                      | ((unsigned long long)(unsigned)dsts[k] << 16)
                      | (unsigned long long)f32_to_bf16_rne(ee);
    }
}

// ---------------------------------------------------------------------------
// Kernel 3: fused CSR finalize + SpMM + finalize.
// R4: SBW=64 buckets, 512-thread blocks, ~31 KB LDS -> 4 blocks/CU (100%
// wave slots, was 16 waves + 60 idle CUs). SpMM: each 8-lane group owns one
// row (lane = 8-feature slice); lpair reads broadcast within the group;
// NO cross-lane reduction; all 8 lanes store disjoint 16 B output slices.
// ---------------------------------------------------------------------------
__global__ __launch_bounds__(512) void csr_spmm_kernel(
    const int* __restrict__ bcur,
    const unsigned long long* __restrict__ recs,
    const unsigned short* __restrict__ h,   // bf16 [NN, FOUT]
    const int* __restrict__ flags,
    void* __restrict__ out)
{
    __shared__ unsigned long long lrec[CAPB];   // 20 KB
    __shared__ unsigned int lpair[CAPB];        // 10 KB
    __shared__ int cnt[SBW];
    __shared__ int off[SBW];
    const int b    = blockIdx.x;
    const int tid  = threadIdx.x;
    const int rb   = b * SBW;
    const int beg  = b * RCAP;

    int n = bcur[b]; if (n > RCAP) n = RCAP;

    if (tid < SBW) cnt[tid] = 0;
    __syncthreads();

    // pass 1: load + count + rank; repack hi32 = r | rank<<8 (r<64, rank<2^12)
    for (int j = tid; j < n; j += 512) {
        const unsigned long long rec = recs[beg + j];
        const int r = (int)(rec >> 32) - rb;
        const int rank = atomicAdd(&cnt[r], 1);
        lrec[j] = ((unsigned long long)(unsigned)(r | (rank << 8)) << 32)
                | (unsigned long long)(unsigned)(rec & 0xFFFFFFFFu);
    }
    __syncthreads();

    // exclusive scan of the 64 counters by wave 0 (cnt preserved = row length)
    if (tid < SBW) {
        const int c = cnt[tid];
        int x = c;
        #pragma unroll
        for (int o = 1; o < SBW; o <<= 1) {
            int y = __shfl_up(x, o, 64);
            if (tid >= o) x += y;
        }
        off[tid] = x - c;
    }
    __syncthreads();

    // pass 2: atomic-free scatter into row-grouped lpair
    for (int j = tid; j < n; j += 512) {
        const unsigned long long rec = lrec[j];
        const unsigned int hi = (unsigned int)(rec >> 32);
        lpair[off[hi & 63u] + (hi >> 8)] = (unsigned int)(rec & 0xFFFFFFFFu);
    }
    __syncthreads();

    // ---- SpMM: 8 waves x 8 groups; group (wv,gr) owns row rb + wv*8 + gr ----
    const int wv   = tid >> 6;
    const int lane = tid & 63;
    const int gr   = lane >> 3;          // row-group within wave
    const int sl   = lane & 7;           // features 8*sl .. 8*sl+7
    const int rr   = wv * 8 + gr;        // 0..63
    const int row  = rb + rr;
    const int fOut = flags[0];

    const int jb = off[rr];
    const int je = jb + cnt[rr];

    float acc0 = 0.f, acc1 = 0.f, acc2 = 0.f, acc3 = 0.f;
    float acc4 = 0.f, acc5 = 0.f, acc6 = 0.f, acc7 = 0.f;
    float rsum = 0.f;
    int j = jb;
    for (; j + 3 < je; j += 4) {         // 4 gathers in flight per lane
        unsigned int u[4];
        #pragma unroll
        for (int kk = 0; kk < 4; ++kk) u[kk] = lpair[j + kk];   // group-broadcast
        ushort8v hv[4];
        #pragma unroll
        for (int kk = 0; kk < 4; ++kk)
            hv[kk] = *(const ushort8v*)&h[(long)(u[kk] >> 16) * FOUT + 8 * sl];
        #pragma unroll
        for (int kk = 0; kk < 4; ++kk) {
            const float v = bf16_to_f32((unsigned short)(u[kk] & 0xFFFFu));
            rsum += v;
            acc0 = fmaf(v, bf16_to_f32(hv[kk][0]), acc0);
            acc1 = fmaf(v, bf16_to_f32(hv[kk][1]), acc1);
            acc2 = fmaf(v, bf16_to_f32(hv[kk][2]), acc2);
            acc3 = fmaf(v, bf16_to_f32(hv[kk][3]), acc3);
            acc4 = fmaf(v, bf16_to_f32(hv[kk][4]), acc4);
            acc5 = fmaf(v, bf16_to_f32(hv[kk][5]), acc5);
            acc6 = fmaf(v, bf16_to_f32(hv[kk][6]), acc6);
            acc7 = fmaf(v, bf16_to_f32(hv[kk][7]), acc7);
        }
    }
    for (; j < je; ++j) {                // tail
        const unsigned int u = lpair[j];
        const ushort8v hv = *(const ushort8v*)&h[(long)(u >> 16) * FOUT + 8 * sl];
        const float v = bf16_to_f32((unsigned short)(u & 0xFFFFu));
        rsum += v;
        acc0 = fmaf(v, bf16_to_f32(hv[0]), acc0);
        acc1 = fmaf(v, bf16_to_f32(hv[1]), acc1);
        acc2 = fmaf(v, bf16_to_f32(hv[2]), acc2);
        acc3 = fmaf(v, bf16_to_f32(hv[3]), acc3);
        acc4 = fmaf(v, bf16_to_f32(hv[4]), acc4);
        acc5 = fmaf(v, bf16_to_f32(hv[5]), acc5);
        acc6 = fmaf(v, bf16_to_f32(hv[6]), acc6);
        acc7 = fmaf(v, bf16_to_f32(hv[7]), acc7);
    }

    if (row < NN && je > jb) {
        const float inv = 1.f / rsum;    // identical across the 8 lanes
        float q0 = acc0 * inv, q1 = acc1 * inv, q2 = acc2 * inv, q3 = acc3 * inv;
        float q4 = acc4 * inv, q5 = acc5 * inv, q6 = acc6 * inv, q7 = acc7 * inv;
        q0 = q0 > 0.f ? q0 : (__expf(q0) - 1.f);
        q1 = q1 > 0.f ? q1 : (__expf(q1) - 1.f);
        q2 = q2 > 0.f ? q2 : (__expf(q2) - 1.f);
        q3 = q3 > 0.f ? q3 : (__expf(q3) - 1.f);
        q4 = q4 > 0.f ? q4 : (__expf(q4) - 1.f);
        q5 = q5 > 0.f ? q5 : (__expf(q5) - 1.f);
        q6 = q6 > 0.f ? q6 : (__expf(q6) - 1.f);
        q7 = q7 > 0.f ? q7 : (__expf(q7) - 1.f);
        if (fOut) {
            float4* o = (float4*)((float*)out + (long)row * FOUT + 8 * sl);
            o[0] = make_float4(q0, q1, q2, q3);
            o[1] = make_float4(q4, q5, q6, q7);
        } else {
            ushort8v ov;
            ov[0] = f32_to_bf16_rne(q0); ov[1] = f32_to_bf16_rne(q1);
            ov[2] = f32_to_bf16_rne(q2); ov[3] = f32_to_bf16_rne(q3);
            ov[4] = f32_to_bf16_rne(q4); ov[5] = f32_to_bf16_rne(q5);
            ov[6] = f32_to_bf16_rne(q6); ov[7] = f32_to_bf16_rne(q7);
            *(ushort8v*)((unsigned short*)out + (long)row * FOUT + 8 * sl) = ov;
        }
    } else if (row < NN) {               // empty row: rsum=0 -> 0/0; emit 0
        if (fOut) {
            float4* o = (float4*)((float*)out + (long)row * FOUT + 8 * sl);
            o[0] = make_float4(0.f, 0.f, 0.f, 0.f);
            o[1] = make_float4(0.f, 0.f, 0.f, 0.f);
        } else {
            ushort8v ov = { 0, 0, 0, 0, 0, 0, 0, 0 };
            *(ushort8v*)((unsigned short*)out + (long)row * FOUT + 8 * sl) = ov;
        }
    }
}

extern "C" void kernel_launch(void* const* d_in, const int* in_sizes, int n_in,
                              void* d_out, int out_size, void* d_ws, size_t ws_size,
                              hipStream_t stream) {
    const void* inp  = d_in[0];
    const void* Mv   = d_in[1];
    const void* W    = d_in[2];
    const void* a    = d_in[3];
    const int*  edge = (const int*)d_in[4];

    // ws: flags | Wt bf16[64*128] | h bf16[NN*64] | s1[NN] | s2[NN] | bcur[NB] | recs u64[NB*RCAP]
    char* p = (char*)d_ws;
    int*                flags  = (int*)p;            p += 256;
    unsigned short*     Wt     = (unsigned short*)p; p += ((size_t)FOUT * FIN * 2 + 255) / 256 * 256;
    unsigned short*     h      = (unsigned short*)p; p += ((size_t)NN * FOUT * 2 + 255) / 256 * 256;
    float*              s1     = (float*)p;          p += ((size_t)NN * 4 + 255) / 256 * 256;
    float*              s2     = (float*)p;          p += ((size_t)NN * 4 + 255) / 256 * 256;
    int*                bcur   = (int*)p;            p += ((size_t)NB * 4 + 255) / 256 * 256;
    unsigned long long* recs   = (unsigned long long*)p;

    detwt_kernel<<<32, 256, 0, stream>>>(W, Mv, Wt, flags, bcur);
    mfma_gemm_kernel<<<NN / 16, 256, 0, stream>>>(inp, Wt, a, h, s1, s2, flags);
    partition_kernel<<<PGRID, 1024, 0, stream>>>(edge, Mv, flags, s1, s2, bcur, recs);
    csr_spmm_kernel<<<NB, 512, 0, stream>>>(bcur, recs, h, flags, d_out);
}